// Round 11
// baseline (370.409 us; speedup 1.0000x reference)
//
#include <hip/hip_runtime.h>
#include <stdint.h>

#define AS1 __attribute__((address_space(1)))
#define AS3 __attribute__((address_space(3)))

typedef __attribute__((ext_vector_type(4))) float f32x4;
typedef __attribute__((ext_vector_type(8))) short s16x8;
typedef __attribute__((ext_vector_type(4))) short s16x4;

static constexpr int NTOK = 16384;
static constexpr int H    = 1024;
static constexpr int F    = 2048;
static constexpr int TWOF = 4096;
static constexpr int NEXP = 8;
static constexpr int MP2  = NTOK + NEXP * 256;     // 18432 padded rows
static constexpr int MAXT256 = NTOK / 256 + NEXP;  // 72
static constexpr int MAXT128 = 2 * MAXT256;        // 144

__device__ __forceinline__ ushort f2bf(float f) {
  union { float fv; uint32_t u; } v; v.fv = f;
  return (ushort)((v.u + 0x7FFFu + ((v.u >> 16) & 1u)) >> 16);
}

__device__ __forceinline__ void gload_lds16(const void* g, void* l) {
  __builtin_amdgcn_global_load_lds((const AS1 uint32_t*)g, (AS3 uint32_t*)l, 16, 0, 0);
}

#define BAR() do { asm volatile("" ::: "memory"); __builtin_amdgcn_s_barrier(); asm volatile("" ::: "memory"); } while (0)
#define VM4() asm volatile("s_waitcnt vmcnt(4)" ::: "memory")
#define VM0() asm volatile("s_waitcnt vmcnt(0)" ::: "memory")

// common transpose body: one 64x64 tile of src[K][N] fp32 -> dst[N][K] bf16
__device__ __forceinline__ void tp_tile(const float* __restrict__ s,
                                        ushort* __restrict__ d, int K, int N) {
  __shared__ __align__(16) ushort t[64 * 68];
  int tid = threadIdx.x;
#pragma unroll
  for (int r = 0; r < 4; ++r) {
    int i = r * 1024 + tid * 4;
    int kl = i >> 6, nl = i & 63;
    f32x4 v = *(const f32x4*)(s + (size_t)kl * N + nl);
    t[(nl + 0) * 68 + kl] = f2bf(v.x);
    t[(nl + 1) * 68 + kl] = f2bf(v.y);
    t[(nl + 2) * 68 + kl] = f2bf(v.z);
    t[(nl + 3) * 68 + kl] = f2bf(v.w);
  }
  __syncthreads();
#pragma unroll
  for (int r = 0; r < 2; ++r) {
    int i = r * 2048 + tid * 8;
    int nl = i >> 6, k8 = i & 63;
    s16x4 v0 = *(const s16x4*)&t[nl * 68 + k8];
    s16x4 v1 = *(const s16x4*)&t[nl * 68 + k8 + 4];
    *(s16x4*)(d + (size_t)nl * K + k8) = v0;
    *(s16x4*)(d + (size_t)nl * K + k8 + 4) = v1;
  }
}

// prep: z<8 -> wgu transpose, 8<=z<16 -> wdn transpose, z==16 (block 0,0) -> routing
__global__ void k_prep(const float* __restrict__ wgu, ushort* __restrict__ gdst,
                       const float* __restrict__ wdn, ushort* __restrict__ ddst,
                       const int* __restrict__ eid, int* __restrict__ meta,
                       int* __restrict__ sidx) {
  int nt = blockIdx.x, kt = blockIdx.y, z = blockIdx.z;
  if (z < NEXP) {
    if (nt >= TWOF / 64 || kt >= H / 64) return;
    const float* s = wgu + (size_t)z * H * TWOF + (size_t)(kt * 64) * TWOF + nt * 64;
    ushort* d = gdst + (size_t)z * TWOF * H + (size_t)(nt * 64) * H + kt * 64;
    tp_tile(s, d, H, TWOF);
  } else if (z < 2 * NEXP) {
    int e = z - NEXP;
    if (nt >= H / 64 || kt >= F / 64) return;
    const float* s = wdn + (size_t)e * F * H + (size_t)(kt * 64) * H + nt * 64;
    ushort* d = ddst + (size_t)e * H * F + (size_t)(nt * 64) * F + kt * 64;
    tp_tile(s, d, F, H);
  } else {
    if (nt != 0 || kt != 0) return;
    __shared__ int cnt[NEXP];
    __shared__ int base[NEXP];
    __shared__ int cur[NEXP];
    const int tid = threadIdx.x;
    if (tid < NEXP) { cnt[tid] = 0; cur[tid] = 0; }
    __syncthreads();
    for (int i = tid; i < MP2; i += 256) sidx[i] = -1;
    for (int i = tid; i < NTOK; i += 256) atomicAdd(&cnt[eid[i]], 1);
    __syncthreads();
    if (tid == 0) {
      int prow = 0, n256 = 0, n128 = 0;
      meta[16] = 0;
      for (int e = 0; e < NEXP; ++e) {
        int c = cnt[e];
        base[e] = prow;
        int ntl = (c + 255) >> 8;
        for (int k = 0; k < ntl; ++k) {
          meta[64 + n256] = e;  meta[256 + n256] = prow;  ++n256;
          meta[512 + n128] = e; meta[768 + n128] = prow;  ++n128;
          if (k * 256 + 128 < c) {
            meta[512 + n128] = e; meta[768 + n128] = prow + 128; ++n128;
          }
          prow += 256;
        }
        meta[16 + e + 1] = prow;
      }
      meta[48] = n256; meta[49] = n128;
    }
    __syncthreads();
    for (int i = tid; i < NTOK; i += 256) {
      int e = eid[i];
      int pos = base[e] + atomicAdd(&cur[e], 1);
      sidx[pos] = i;
    }
  }
}

__global__ void k_gather(const float* __restrict__ tok, const int* __restrict__ sidx,
                         ushort* __restrict__ A) {
  int t = blockIdx.x * blockDim.x + threadIdx.x;
  long flat = (long)t * 8;
  int row = (int)(flat >> 10), col = (int)(flat & 1023);
  if (row >= MP2) return;
  int idx = sidx[row];
  s16x8 o = (s16x8)0;
  if (idx >= 0) {
    const f32x4* p = (const f32x4*)(tok + (size_t)idx * H + col);
    f32x4 a = p[0], b = p[1];
    o[0] = (short)f2bf(a.x); o[1] = (short)f2bf(a.y);
    o[2] = (short)f2bf(a.z); o[3] = (short)f2bf(a.w);
    o[4] = (short)f2bf(b.x); o[5] = (short)f2bf(b.y);
    o[6] = (short)f2bf(b.z); o[7] = (short)f2bf(b.w);
  }
  *(s16x8*)(A + flat) = o;
}

// ---------------- GEMM1: 256x128 tile, BK=64, 8-phase (frozen) -------------------------
__global__ __launch_bounds__(512, 2)
void k_gemm1(const ushort* __restrict__ A, const ushort* __restrict__ Wt,
             ushort* __restrict__ Hid, const int* __restrict__ meta) {
  int lin = blockIdx.x;
  int swz = (lin & 7) * (MAXT256 * 16 / 8) + (lin >> 3);
  int t = swz >> 4, ct = swz & 15;
  if (t >= meta[48]) return;
  int e = meta[64 + t], row0 = meta[256 + t];

  extern __shared__ __align__(16) char smem[];
  ushort* sA0 = (ushort*)smem;             // [256][64]
  ushort* sA1 = (ushort*)(smem + 32768);
  ushort* sB0 = (ushort*)(smem + 65536);   // [256][64] (128 gate + 128 up rows)
  ushort* sB1 = (ushort*)(smem + 98304);

  const int tid = threadIdx.x, lane = tid & 63, wid = tid >> 6;
  const int wm = wid >> 2, wn = wid & 3;
  const int l15 = lane & 15, g = lane >> 4;

  const int swzblk = (tid & 7) ^ ((tid >> 3) & 7);
  const ushort* aGbase = A + (size_t)(row0 + (tid >> 3)) * H + swzblk * 8;
  const int s63 = tid >> 3;
  const int up = s63 >> 5;
  const int cc = s63 & 31;
  const ushort* bGbase = Wt + (size_t)e * TWOF * H
                       + (size_t)(up * F + ct * 128 + cc) * H + swzblk * 8;

  auto stageA = [&](ushort* dst, int h, int kt) {
    gload_lds16(aGbase + (size_t)(h * 128) * H + kt * 64,      dst + h * 8192 + wid * 512);
    gload_lds16(aGbase + (size_t)(h * 128 + 64) * H + kt * 64, dst + h * 8192 + 4096 + wid * 512);
  };
  auto stageB = [&](ushort* dst, int h, int kt) {
    gload_lds16(bGbase + (size_t)(h * 64) * H + kt * 64,       dst + h * 8192 + wid * 512);
    gload_lds16(bGbase + (size_t)(h * 64 + 32) * H + kt * 64,  dst + h * 8192 + 4096 + wid * 512);
  };

  f32x4 acc[8][4] = {};
  s16x8 bf[2][4];

  auto rdB = [&](const ushort* sBb) {
#pragma unroll
    for (int ks = 0; ks < 2; ++ks)
#pragma unroll
      for (int nf = 0; nf < 4; ++nf) {
        int r = wn * 64 + nf * 16 + l15;
        bf[ks][nf] = *(const s16x8*)(sBb + r * 64 + (((ks * 4 + g) ^ (l15 & 7)) << 3));
      }
  };

#define PHASE(sAb, Q, RDB_STMT, STAGE_STMT, VM_STMT) do {                         \
    RDB_STMT;                                                                     \
    s16x8 af[2][2];                                                               \
    _Pragma("unroll") for (int ks = 0; ks < 2; ++ks)                              \
      _Pragma("unroll") for (int mf = 0; mf < 2; ++mf) {                          \
        int r = wm * 128 + (Q) * 32 + mf * 16 + l15;                              \
        af[mf][ks] = *(const s16x8*)((sAb) + r * 64 + (((ks * 4 + g) ^ (l15 & 7)) << 3)); \
      }                                                                           \
    STAGE_STMT;                                                                   \
    BAR();                                                                        \
    __builtin_amdgcn_s_setprio(1);                                                \
    _Pragma("unroll") for (int ks = 0; ks < 2; ++ks)                              \
      _Pragma("unroll") for (int mf = 0; mf < 2; ++mf)                            \
        _Pragma("unroll") for (int nf = 0; nf < 4; ++nf)                          \
          acc[(Q) * 2 + mf][nf] = __builtin_amdgcn_mfma_f32_16x16x32_bf16(        \
              af[mf][ks], bf[ks][nf], acc[(Q) * 2 + mf][nf], 0, 0, 0);            \
    __builtin_amdgcn_s_setprio(0);                                                \
    VM_STMT;                                                                      \
    BAR();                                                                        \
  } while (0)

  constexpr int nkt = H / 64;     // 16
  constexpr int nit = nkt / 2;    // 8

  stageA(sA0, 0, 0); stageA(sA0, 1, 0);
  stageB(sB0, 0, 0); stageB(sB0, 1, 0);
  stageB(sB1, 0, 1); stageB(sB1, 1, 1);
  VM4();
  BAR();

#pragma unroll 1
  for (int i = 0; i < nit; ++i) {
    const int T1 = 2 * i + 1;
    const bool more = (i < nit - 1);
    PHASE(sA0, 0, rdB(sB0), stageA(sA1, 0, T1), ((void)0));
    PHASE(sA0, 1, ((void)0), stageA(sA1, 1, T1), ((void)0));
    PHASE(sA0, 2, ((void)0), if (more) stageB(sB0, 0, T1 + 1), ((void)0));
    PHASE(sA0, 3, ((void)0), if (more) stageB(sB0, 1, T1 + 1), if (more) VM4(); else VM0());
    PHASE(sA1, 0, rdB(sB1), if (more) stageA(sA0, 0, T1 + 1), ((void)0));
    PHASE(sA1, 1, ((void)0), if (more) stageA(sA0, 1, T1 + 1), ((void)0));
    PHASE(sA1, 2, ((void)0), if (more) stageB(sB1, 0, T1 + 2), ((void)0));
    PHASE(sA1, 3, ((void)0), if (more) stageB(sB1, 1, T1 + 2), if (more) VM4(); else ((void)0));
  }
#undef PHASE

  const int g4 = g * 4;
#pragma unroll
  for (int m = 0; m < 8; ++m)
#pragma unroll
    for (int nf = 0; nf < 2; ++nf)
#pragma unroll
      for (int j = 0; j < 4; ++j) {
        float gv = acc[m][nf][j], uv = acc[m][nf + 2][j];
        float h = gv / (1.0f + __expf(-gv)) * uv;
        int row = row0 + wm * 128 + m * 16 + g4 + j;
        int col = ct * 128 + wn * 32 + nf * 16 + l15;
        Hid[(size_t)row * F + col] = f2bf(h);
      }
}

// ---------------- GEMM2: 128x128 tile, 4 waves, 16-MFMA cadence (frozen) ---------------
__global__ __launch_bounds__(256, 2)
void k_gemm2(const ushort* __restrict__ Hid, const ushort* __restrict__ Wt,
             float* __restrict__ Out, const int* __restrict__ meta,
             const int* __restrict__ sidx) {
  int lin = blockIdx.x;
  int swz = (lin & 7) * (MAXT128 * 8 / 8) + (lin >> 3);
  int t = swz >> 3, ct = swz & 7;
  if (t >= meta[49]) return;
  int e = meta[512 + t], row0 = meta[768 + t];

  extern __shared__ __align__(16) char smem[];
  ushort* sA0 = (ushort*)smem;             // [128][64] = 16KB each
  ushort* sA1 = (ushort*)(smem + 16384);
  ushort* sB0 = (ushort*)(smem + 32768);
  ushort* sB1 = (ushort*)(smem + 49152);

  const int tid = threadIdx.x, lane = tid & 63, wid = tid >> 6;  // 4 waves: 2M x 2N
  const int wm = wid >> 1, wn = wid & 1;
  const int l15 = lane & 15, g = lane >> 4;

  const int swzblk = (tid & 7) ^ ((tid >> 3) & 7);
  const int r32 = tid >> 3;  // 0..31
  const ushort* aGbase = Hid + (size_t)(row0 + r32) * F + swzblk * 8;
  const ushort* bGbase = Wt + (size_t)e * H * F + (size_t)(ct * 128 + r32) * F + swzblk * 8;

  auto stageA = [&](ushort* dst, int h, int kt) {
    gload_lds16(aGbase + (size_t)(h * 64) * F + kt * 64,      dst + h * 4096 + wid * 512);
    gload_lds16(aGbase + (size_t)(h * 64 + 32) * F + kt * 64, dst + h * 4096 + 2048 + wid * 512);
  };
  auto stageB = [&](ushort* dst, int h, int kt) {
    gload_lds16(bGbase + (size_t)(h * 64) * F + kt * 64,      dst + h * 4096 + wid * 512);
    gload_lds16(bGbase + (size_t)(h * 64 + 32) * F + kt * 64, dst + h * 4096 + 2048 + wid * 512);
  };

  f32x4 acc[4][4] = {};   // [m = Q*2+mf][nf]
  s16x8 bf[2][4];

  auto rdB = [&](const ushort* sBb) {
#pragma unroll
    for (int ks = 0; ks < 2; ++ks)
#pragma unroll
      for (int nf = 0; nf < 4; ++nf) {
        int r = wn * 64 + nf * 16 + l15;
        bf[ks][nf] = *(const s16x8*)(sBb + r * 64 + (((ks * 4 + g) ^ (l15 & 7)) << 3));
      }
  };

#define PHASE2(sAb, Q, RDB_STMT, STAGE_STMT, VM_STMT) do {                        \
    RDB_STMT;                                                                     \
    s16x8 af[2][2];                                                               \
    _Pragma("unroll") for (int ks = 0; ks < 2; ++ks)                              \
      _Pragma("unroll") for (int mf = 0; mf < 2; ++mf) {                          \
        int r = wm * 64 + (Q) * 32 + mf * 16 + l15;                               \
        af[mf][ks] = *(const s16x8*)((sAb) + r * 64 + (((ks * 4 + g) ^ (l15 & 7)) << 3)); \
      }                                                                           \
    STAGE_STMT;                                                                   \
    BAR();                                                                        \
    __builtin_amdgcn_s_setprio(1);                                                \
    _Pragma("unroll") for (int ks = 0; ks < 2; ++ks)                              \
      _Pragma("unroll") for (int mf = 0; mf < 2; ++mf)                            \
        _Pragma("unroll") for (int nf = 0; nf < 4; ++nf)                          \
          acc[(Q) * 2 + mf][nf] = __builtin_amdgcn_mfma_f32_16x16x32_bf16(        \
              af[mf][ks], bf[ks][nf], acc[(Q) * 2 + mf][nf], 0, 0, 0);            \
    __builtin_amdgcn_s_setprio(0);                                                \
    VM_STMT;                                                                      \
    BAR();                                                                        \
  } while (0)

  constexpr int nkt = F / 64;     // 32
  constexpr int nit = nkt / 2;    // 16

  stageA(sA0, 0, 0); stageA(sA0, 1, 0);
  stageB(sB0, 0, 0); stageB(sB0, 1, 0);
  stageB(sB1, 0, 1); stageB(sB1, 1, 1);
  VM4();
  BAR();

#pragma unroll 1
  for (int i = 0; i < nit; ++i) {
    const int T1 = 2 * i + 1;
    const bool more = (i < nit - 1);
    PHASE2(sA0, 0, rdB(sB0), { stageA(sA1, 0, T1); stageA(sA1, 1, T1); }, ((void)0));
    PHASE2(sA0, 1, ((void)0),
           if (more) { stageB(sB0, 0, T1 + 1); stageB(sB0, 1, T1 + 1); },
           if (more) VM4(); else VM0());
    PHASE2(sA1, 0, rdB(sB1),
           if (more) { stageA(sA0, 0, T1 + 1); stageA(sA0, 1, T1 + 1); }, ((void)0));
    PHASE2(sA1, 1, ((void)0),
           if (more) { stageB(sB1, 0, T1 + 2); stageB(sB1, 1, T1 + 2); },
           if (more) VM4());
  }
#undef PHASE2

  const int g4 = g * 4;
#pragma unroll
  for (int m = 0; m < 4; ++m)
#pragma unroll
    for (int j = 0; j < 4; ++j) {
      int prow = row0 + wm * 64 + m * 16 + g4 + j;
      int orig = sidx[prow];
      if (orig >= 0) {
#pragma unroll
        for (int nf = 0; nf < 4; ++nf) {
          int col = ct * 128 + wn * 64 + nf * 16 + l15;
          Out[(size_t)orig * H + col] = acc[m][nf][j];
        }
      }
    }
}

extern "C" void kernel_launch(void* const* d_in, const int* in_sizes, int n_in,
                              void* d_out, int out_size, void* d_ws, size_t ws_size,
                              hipStream_t stream) {
  (void)in_sizes; (void)n_in; (void)out_size;
  const float* tokens = (const float*)d_in[0];
  const float* wgu    = (const float*)d_in[1];
  const float* wdn    = (const float*)d_in[2];
  const int*   eid    = (const int*)d_in[3];

  char* ws = (char*)d_ws;
  int*    meta  = (int*)ws;                       // 8 KB
  int*    sidx  = (int*)(ws + 8192);              // 18432 ints
  ushort* Abf   = (ushort*)(ws + 131072);                         // 37,748,736 B
  ushort* Hid   = (ushort*)(ws + 131072 + 37748736);              // 75,497,472 B
  ushort* Wgu_t = (ushort*)(ws + 131072 + 37748736 + 75497472);   // 67,108,864 B
  ushort* Wdn_t = (ushort*)(ws + 131072 + 37748736 + 75497472 + 67108864);  // 33,554,432 B

  hipFuncSetAttribute((const void*)k_gemm1,
                      hipFuncAttributeMaxDynamicSharedMemorySize, 131072);
  hipFuncSetAttribute((const void*)k_gemm2,
                      hipFuncAttributeMaxDynamicSharedMemorySize, 65536);

  // prep: both weight transposes + routing in one dispatch (route hides under transpose)
  k_prep   <<<dim3(TWOF / 64, F / 64, 2 * NEXP + 1), 256, 0, stream>>>(
      wgu, Wgu_t, wdn, Wdn_t, eid, meta, sidx);
  k_gather <<<MP2 * H / 8 / 256, 256, 0, stream>>>(tokens, sidx, Abf);
  k_gemm1  <<<MAXT256 * 16, 512, 131072, stream>>>(Abf, Wgu_t, Hid, meta);
  k_gemm2  <<<MAXT128 * 8, 256, 65536, stream>>>(Hid, Wdn_t, (float*)d_out, meta, sidx);
}

// Round 12
// 354.064 us; speedup vs baseline: 1.0462x; 1.0462x over previous
//
#include <hip/hip_runtime.h>
#include <stdint.h>

#define AS1 __attribute__((address_space(1)))
#define AS3 __attribute__((address_space(3)))

typedef __attribute__((ext_vector_type(4))) float f32x4;
typedef __attribute__((ext_vector_type(8))) short s16x8;
typedef __attribute__((ext_vector_type(4))) short s16x4;

static constexpr int NTOK = 16384;
static constexpr int H    = 1024;
static constexpr int F    = 2048;
static constexpr int TWOF = 4096;
static constexpr int NEXP = 8;
static constexpr int MP2  = NTOK + NEXP * 256;     // 18432 padded rows
static constexpr int MAXT256 = NTOK / 256 + NEXP;  // 72
static constexpr int MAXT128 = 2 * MAXT256;        // 144

__device__ __forceinline__ ushort f2bf(float f) {
  union { float fv; uint32_t u; } v; v.fv = f;
  return (ushort)((v.u + 0x7FFFu + ((v.u >> 16) & 1u)) >> 16);
}

__device__ __forceinline__ void gload_lds16(const void* g, void* l) {
  __builtin_amdgcn_global_load_lds((const AS1 uint32_t*)g, (AS3 uint32_t*)l, 16, 0, 0);
}

#define BAR() do { asm volatile("" ::: "memory"); __builtin_amdgcn_s_barrier(); asm volatile("" ::: "memory"); } while (0)
#define VM4() asm volatile("s_waitcnt vmcnt(4)" ::: "memory")
#define VM0() asm volatile("s_waitcnt vmcnt(0)" ::: "memory")

// ---- routing: histogram + scan + tile tables + scatter, one block ----------
__global__ __launch_bounds__(1024)
void k_route(const int* __restrict__ eid, int* __restrict__ meta,
             int* __restrict__ sidx) {
  __shared__ int cnt[NEXP];
  __shared__ int base[NEXP];
  __shared__ int cur[NEXP];
  const int tid = threadIdx.x;
  if (tid < NEXP) { cnt[tid] = 0; cur[tid] = 0; }
  __syncthreads();
  for (int i = tid; i < MP2; i += 1024) sidx[i] = -1;
  for (int i = tid; i < NTOK; i += 1024) atomicAdd(&cnt[eid[i]], 1);
  __syncthreads();
  if (tid == 0) {
    int prow = 0, n256 = 0, n128 = 0;
    meta[16] = 0;
    for (int e = 0; e < NEXP; ++e) {
      int c = cnt[e];
      base[e] = prow;
      int nt = (c + 255) >> 8;
      for (int k = 0; k < nt; ++k) {
        meta[64 + n256] = e;  meta[256 + n256] = prow;  ++n256;
        meta[512 + n128] = e; meta[768 + n128] = prow;  ++n128;
        if (k * 256 + 128 < c) {
          meta[512 + n128] = e; meta[768 + n128] = prow + 128; ++n128;
        }
        prow += 256;
      }
      meta[16 + e + 1] = prow;
    }
    meta[48] = n256; meta[49] = n128;
  }
  __syncthreads();
  for (int i = tid; i < NTOK; i += 1024) {
    int e = eid[i];
    int pos = base[e] + atomicAdd(&cur[e], 1);
    sidx[pos] = i;
  }
}

__global__ void k_gather(const float* __restrict__ tok, const int* __restrict__ sidx,
                         ushort* __restrict__ A) {
  int t = blockIdx.x * blockDim.x + threadIdx.x;
  long flat = (long)t * 8;
  int row = (int)(flat >> 10), col = (int)(flat & 1023);
  if (row >= MP2) return;
  int idx = sidx[row];
  s16x8 o = (s16x8)0;
  if (idx >= 0) {
    const f32x4* p = (const f32x4*)(tok + (size_t)idx * H + col);
    f32x4 a = p[0], b = p[1];
    o[0] = (short)f2bf(a.x); o[1] = (short)f2bf(a.y);
    o[2] = (short)f2bf(a.z); o[3] = (short)f2bf(a.w);
    o[4] = (short)f2bf(b.x); o[5] = (short)f2bf(b.y);
    o[6] = (short)f2bf(b.z); o[7] = (short)f2bf(b.w);
  }
  *(s16x8*)(A + flat) = o;
}

// common transpose body: one 64x64 tile of src[K][N] fp32 -> dst[N][K] bf16
__device__ __forceinline__ void tp_tile(const float* __restrict__ s,
                                        ushort* __restrict__ d, int K, int N) {
  __shared__ __align__(16) ushort t[64 * 68];
  int tid = threadIdx.x;
#pragma unroll
  for (int r = 0; r < 4; ++r) {
    int i = r * 1024 + tid * 4;
    int kl = i >> 6, nl = i & 63;
    f32x4 v = *(const f32x4*)(s + (size_t)kl * N + nl);
    t[(nl + 0) * 68 + kl] = f2bf(v.x);
    t[(nl + 1) * 68 + kl] = f2bf(v.y);
    t[(nl + 2) * 68 + kl] = f2bf(v.z);
    t[(nl + 3) * 68 + kl] = f2bf(v.w);
  }
  __syncthreads();
#pragma unroll
  for (int r = 0; r < 2; ++r) {
    int i = r * 2048 + tid * 8;
    int nl = i >> 6, k8 = i & 63;
    s16x4 v0 = *(const s16x4*)&t[nl * 68 + k8];
    s16x4 v1 = *(const s16x4*)&t[nl * 68 + k8 + 4];
    *(s16x4*)(d + (size_t)nl * K + k8) = v0;
    *(s16x4*)(d + (size_t)nl * K + k8 + 4) = v1;
  }
}

// merged transpose: z<8 -> wgu (K=1024,N=4096), z>=8 -> wdn (K=2048,N=1024)
__global__ void k_transpose_all(const float* __restrict__ wgu, ushort* __restrict__ gdst,
                                const float* __restrict__ wdn, ushort* __restrict__ ddst) {
  int nt = blockIdx.x, kt = blockIdx.y, z = blockIdx.z;
  if (z < NEXP) {
    if (nt >= TWOF / 64 || kt >= H / 64) return;
    const float* s = wgu + (size_t)z * H * TWOF + (size_t)(kt * 64) * TWOF + nt * 64;
    ushort* d = gdst + (size_t)z * TWOF * H + (size_t)(nt * 64) * H + kt * 64;
    tp_tile(s, d, H, TWOF);
  } else {
    int e = z - NEXP;
    if (nt >= H / 64 || kt >= F / 64) return;
    const float* s = wdn + (size_t)e * F * H + (size_t)(kt * 64) * H + nt * 64;
    ushort* d = ddst + (size_t)e * H * F + (size_t)(nt * 64) * F + kt * 64;
    tp_tile(s, d, F, H);
  }
}

// ---------------- GEMM1: 256x128 tile, BK=64, 8-phase (frozen) -------------------------
__global__ __launch_bounds__(512, 2)
void k_gemm1(const ushort* __restrict__ A, const ushort* __restrict__ Wt,
             ushort* __restrict__ Hid, const int* __restrict__ meta) {
  int lin = blockIdx.x;
  int swz = (lin & 7) * (MAXT256 * 16 / 8) + (lin >> 3);
  int t = swz >> 4, ct = swz & 15;
  if (t >= meta[48]) return;
  int e = meta[64 + t], row0 = meta[256 + t];

  extern __shared__ __align__(16) char smem[];
  ushort* sA0 = (ushort*)smem;             // [256][64]
  ushort* sA1 = (ushort*)(smem + 32768);
  ushort* sB0 = (ushort*)(smem + 65536);   // [256][64] (128 gate + 128 up rows)
  ushort* sB1 = (ushort*)(smem + 98304);

  const int tid = threadIdx.x, lane = tid & 63, wid = tid >> 6;
  const int wm = wid >> 2, wn = wid & 3;
  const int l15 = lane & 15, g = lane >> 4;

  const int swzblk = (tid & 7) ^ ((tid >> 3) & 7);
  const ushort* aGbase = A + (size_t)(row0 + (tid >> 3)) * H + swzblk * 8;
  const int s63 = tid >> 3;
  const int up = s63 >> 5;
  const int cc = s63 & 31;
  const ushort* bGbase = Wt + (size_t)e * TWOF * H
                       + (size_t)(up * F + ct * 128 + cc) * H + swzblk * 8;

  auto stageA = [&](ushort* dst, int h, int kt) {
    gload_lds16(aGbase + (size_t)(h * 128) * H + kt * 64,      dst + h * 8192 + wid * 512);
    gload_lds16(aGbase + (size_t)(h * 128 + 64) * H + kt * 64, dst + h * 8192 + 4096 + wid * 512);
  };
  auto stageB = [&](ushort* dst, int h, int kt) {
    gload_lds16(bGbase + (size_t)(h * 64) * H + kt * 64,       dst + h * 8192 + wid * 512);
    gload_lds16(bGbase + (size_t)(h * 64 + 32) * H + kt * 64,  dst + h * 8192 + 4096 + wid * 512);
  };

  f32x4 acc[8][4] = {};
  s16x8 bf[2][4];

  auto rdB = [&](const ushort* sBb) {
#pragma unroll
    for (int ks = 0; ks < 2; ++ks)
#pragma unroll
      for (int nf = 0; nf < 4; ++nf) {
        int r = wn * 64 + nf * 16 + l15;
        bf[ks][nf] = *(const s16x8*)(sBb + r * 64 + (((ks * 4 + g) ^ (l15 & 7)) << 3));
      }
  };

#define PHASE(sAb, Q, RDB_STMT, STAGE_STMT, VM_STMT) do {                         \
    RDB_STMT;                                                                     \
    s16x8 af[2][2];                                                               \
    _Pragma("unroll") for (int ks = 0; ks < 2; ++ks)                              \
      _Pragma("unroll") for (int mf = 0; mf < 2; ++mf) {                          \
        int r = wm * 128 + (Q) * 32 + mf * 16 + l15;                              \
        af[mf][ks] = *(const s16x8*)((sAb) + r * 64 + (((ks * 4 + g) ^ (l15 & 7)) << 3)); \
      }                                                                           \
    STAGE_STMT;                                                                   \
    BAR();                                                                        \
    __builtin_amdgcn_s_setprio(1);                                                \
    _Pragma("unroll") for (int ks = 0; ks < 2; ++ks)                              \
      _Pragma("unroll") for (int mf = 0; mf < 2; ++mf)                            \
        _Pragma("unroll") for (int nf = 0; nf < 4; ++nf)                          \
          acc[(Q) * 2 + mf][nf] = __builtin_amdgcn_mfma_f32_16x16x32_bf16(        \
              af[mf][ks], bf[ks][nf], acc[(Q) * 2 + mf][nf], 0, 0, 0);            \
    __builtin_amdgcn_s_setprio(0);                                                \
    VM_STMT;                                                                      \
    BAR();                                                                        \
  } while (0)

  constexpr int nkt = H / 64;     // 16
  constexpr int nit = nkt / 2;    // 8

  stageA(sA0, 0, 0); stageA(sA0, 1, 0);
  stageB(sB0, 0, 0); stageB(sB0, 1, 0);
  stageB(sB1, 0, 1); stageB(sB1, 1, 1);
  VM4();
  BAR();

#pragma unroll 1
  for (int i = 0; i < nit; ++i) {
    const int T1 = 2 * i + 1;
    const bool more = (i < nit - 1);
    PHASE(sA0, 0, rdB(sB0), stageA(sA1, 0, T1), ((void)0));
    PHASE(sA0, 1, ((void)0), stageA(sA1, 1, T1), ((void)0));
    PHASE(sA0, 2, ((void)0), if (more) stageB(sB0, 0, T1 + 1), ((void)0));
    PHASE(sA0, 3, ((void)0), if (more) stageB(sB0, 1, T1 + 1), if (more) VM4(); else VM0());
    PHASE(sA1, 0, rdB(sB1), if (more) stageA(sA0, 0, T1 + 1), ((void)0));
    PHASE(sA1, 1, ((void)0), if (more) stageA(sA0, 1, T1 + 1), ((void)0));
    PHASE(sA1, 2, ((void)0), if (more) stageB(sB1, 0, T1 + 2), ((void)0));
    PHASE(sA1, 3, ((void)0), if (more) stageB(sB1, 1, T1 + 2), if (more) VM4(); else ((void)0));
  }
#undef PHASE

  const int g4 = g * 4;
#pragma unroll
  for (int m = 0; m < 8; ++m)
#pragma unroll
    for (int nf = 0; nf < 2; ++nf)
#pragma unroll
      for (int j = 0; j < 4; ++j) {
        float gv = acc[m][nf][j], uv = acc[m][nf + 2][j];
        float h = gv / (1.0f + __expf(-gv)) * uv;
        int row = row0 + wm * 128 + m * 16 + g4 + j;
        int col = ct * 128 + wn * 32 + nf * 16 + l15;
        Hid[(size_t)row * F + col] = f2bf(h);
      }
}

// ---------------- GEMM2: 128x128 tile, 4 waves, 16-MFMA cadence (frozen) ---------------
__global__ __launch_bounds__(256, 2)
void k_gemm2(const ushort* __restrict__ Hid, const ushort* __restrict__ Wt,
             float* __restrict__ Out, const int* __restrict__ meta,
             const int* __restrict__ sidx) {
  int lin = blockIdx.x;
  int swz = (lin & 7) * (MAXT128 * 8 / 8) + (lin >> 3);
  int t = swz >> 3, ct = swz & 7;
  if (t >= meta[49]) return;
  int e = meta[512 + t], row0 = meta[768 + t];

  extern __shared__ __align__(16) char smem[];
  ushort* sA0 = (ushort*)smem;             // [128][64] = 16KB each
  ushort* sA1 = (ushort*)(smem + 16384);
  ushort* sB0 = (ushort*)(smem + 32768);
  ushort* sB1 = (ushort*)(smem + 49152);

  const int tid = threadIdx.x, lane = tid & 63, wid = tid >> 6;  // 4 waves: 2M x 2N
  const int wm = wid >> 1, wn = wid & 1;
  const int l15 = lane & 15, g = lane >> 4;

  const int swzblk = (tid & 7) ^ ((tid >> 3) & 7);
  const int r32 = tid >> 3;  // 0..31
  const ushort* aGbase = Hid + (size_t)(row0 + r32) * F + swzblk * 8;
  const ushort* bGbase = Wt + (size_t)e * H * F + (size_t)(ct * 128 + r32) * F + swzblk * 8;

  auto stageA = [&](ushort* dst, int h, int kt) {
    gload_lds16(aGbase + (size_t)(h * 64) * F + kt * 64,      dst + h * 4096 + wid * 512);
    gload_lds16(aGbase + (size_t)(h * 64 + 32) * F + kt * 64, dst + h * 4096 + 2048 + wid * 512);
  };
  auto stageB = [&](ushort* dst, int h, int kt) {
    gload_lds16(bGbase + (size_t)(h * 64) * F + kt * 64,      dst + h * 4096 + wid * 512);
    gload_lds16(bGbase + (size_t)(h * 64 + 32) * F + kt * 64, dst + h * 4096 + 2048 + wid * 512);
  };

  f32x4 acc[4][4] = {};   // [m = Q*2+mf][nf]
  s16x8 bf[2][4];

  auto rdB = [&](const ushort* sBb) {
#pragma unroll
    for (int ks = 0; ks < 2; ++ks)
#pragma unroll
      for (int nf = 0; nf < 4; ++nf) {
        int r = wn * 64 + nf * 16 + l15;
        bf[ks][nf] = *(const s16x8*)(sBb + r * 64 + (((ks * 4 + g) ^ (l15 & 7)) << 3));
      }
  };

#define PHASE2(sAb, Q, RDB_STMT, STAGE_STMT, VM_STMT) do {                        \
    RDB_STMT;                                                                     \
    s16x8 af[2][2];                                                               \
    _Pragma("unroll") for (int ks = 0; ks < 2; ++ks)                              \
      _Pragma("unroll") for (int mf = 0; mf < 2; ++mf) {                          \
        int r = wm * 64 + (Q) * 32 + mf * 16 + l15;                               \
        af[mf][ks] = *(const s16x8*)((sAb) + r * 64 + (((ks * 4 + g) ^ (l15 & 7)) << 3)); \
      }                                                                           \
    STAGE_STMT;                                                                   \
    BAR();                                                                        \
    __builtin_amdgcn_s_setprio(1);                                                \
    _Pragma("unroll") for (int ks = 0; ks < 2; ++ks)                              \
      _Pragma("unroll") for (int mf = 0; mf < 2; ++mf)                            \
        _Pragma("unroll") for (int nf = 0; nf < 4; ++nf)                          \
          acc[(Q) * 2 + mf][nf] = __builtin_amdgcn_mfma_f32_16x16x32_bf16(        \
              af[mf][ks], bf[ks][nf], acc[(Q) * 2 + mf][nf], 0, 0, 0);            \
    __builtin_amdgcn_s_setprio(0);                                                \
    VM_STMT;                                                                      \
    BAR();                                                                        \
  } while (0)

  constexpr int nkt = F / 64;     // 32
  constexpr int nit = nkt / 2;    // 16

  stageA(sA0, 0, 0); stageA(sA0, 1, 0);
  stageB(sB0, 0, 0); stageB(sB0, 1, 0);
  stageB(sB1, 0, 1); stageB(sB1, 1, 1);
  VM4();
  BAR();

#pragma unroll 1
  for (int i = 0; i < nit; ++i) {
    const int T1 = 2 * i + 1;
    const bool more = (i < nit - 1);
    PHASE2(sA0, 0, rdB(sB0), { stageA(sA1, 0, T1); stageA(sA1, 1, T1); }, ((void)0));
    PHASE2(sA0, 1, ((void)0),
           if (more) { stageB(sB0, 0, T1 + 1); stageB(sB0, 1, T1 + 1); },
           if (more) VM4(); else VM0());
    PHASE2(sA1, 0, rdB(sB1),
           if (more) { stageA(sA0, 0, T1 + 1); stageA(sA0, 1, T1 + 1); }, ((void)0));
    PHASE2(sA1, 1, ((void)0),
           if (more) { stageB(sB1, 0, T1 + 2); stageB(sB1, 1, T1 + 2); },
           if (more) VM4());
  }
#undef PHASE2

  const int g4 = g * 4;
#pragma unroll
  for (int m = 0; m < 4; ++m)
#pragma unroll
    for (int j = 0; j < 4; ++j) {
      int prow = row0 + wm * 64 + m * 16 + g4 + j;
      int orig = sidx[prow];
      if (orig >= 0) {
#pragma unroll
        for (int nf = 0; nf < 4; ++nf) {
          int col = ct * 128 + wn * 64 + nf * 16 + l15;
          Out[(size_t)orig * H + col] = acc[m][nf][j];
        }
      }
    }
}

extern "C" void kernel_launch(void* const* d_in, const int* in_sizes, int n_in,
                              void* d_out, int out_size, void* d_ws, size_t ws_size,
                              hipStream_t stream) {
  (void)in_sizes; (void)n_in; (void)out_size; (void)ws_size;
  const float* tokens = (const float*)d_in[0];
  const float* wgu    = (const float*)d_in[1];
  const float* wdn    = (const float*)d_in[2];
  const int*   eid    = (const int*)d_in[3];

  char* ws = (char*)d_ws;
  int*    meta  = (int*)ws;                       // 8 KB
  int*    sidx  = (int*)(ws + 8192);              // 18432 ints
  ushort* Abf   = (ushort*)(ws + 131072);                         // 37,748,736 B
  ushort* Hid   = (ushort*)(ws + 131072 + 37748736);              // 75,497,472 B
  ushort* Wgu_t = (ushort*)(ws + 131072 + 37748736 + 75497472);   // 67,108,864 B
  ushort* Wdn_t = (ushort*)(ws + 131072 + 37748736 + 75497472 + 67108864);  // 33,554,432 B

  hipFuncSetAttribute((const void*)k_gemm1,
                      hipFuncAttributeMaxDynamicSharedMemorySize, 131072);
  hipFuncSetAttribute((const void*)k_gemm2,
                      hipFuncAttributeMaxDynamicSharedMemorySize, 65536);

  // one merged transpose dispatch up front; route runs at full 1024-thread width
  k_transpose_all<<<dim3(TWOF / 64, F / 64, 2 * NEXP), 256, 0, stream>>>(
      wgu, Wgu_t, wdn, Wdn_t);
  k_route  <<<1, 1024, 0, stream>>>(eid, meta, sidx);
  k_gather <<<MP2 * H / 8 / 256, 256, 0, stream>>>(tokens, sidx, Abf);
  k_gemm1  <<<MAXT256 * 16, 512, 131072, stream>>>(Abf, Wgu_t, Hid, meta);
  k_gemm2  <<<MAXT128 * 8, 256, 65536, stream>>>(Hid, Wdn_t, (float*)d_out, meta, sidx);
}